// Round 6
// baseline (237.404 us; speedup 1.0000x reference)
//
#include <hip/hip_runtime.h>

// Problem constants
#define TT 4096      // tokens (B*L)
#define DD 1024      // model dim
#define HH 2048      // hidden dim
#define EE 8         // experts
#define TK 8192      // T*K pairs (K=2)

typedef short  bf16x8 __attribute__((ext_vector_type(8)));
typedef float  f32x4  __attribute__((ext_vector_type(4)));

__device__ __forceinline__ unsigned short f2b(float f) {
    unsigned int u = __float_as_uint(f);
    unsigned int r = (u + 0x7fffu + ((u >> 16) & 1u)) >> 16;  // RNE
    return (unsigned short)r;
}
__device__ __forceinline__ float b2f(unsigned short b) {
    return __uint_as_float(((unsigned int)b) << 16);
}

#define GLOAD_LDS16(SRC, DST) __builtin_amdgcn_global_load_lds( \
    (const __attribute__((address_space(1))) unsigned int*)(SRC), \
    (__attribute__((address_space(3))) unsigned int*)(DST), 16, 0, 0)

// ------------- weight transpose + bf16 convert: src [E][Kd][Nd] -> dst [E][Nd][Kd] -------------
__global__ void conv_transpose(const float* __restrict__ src, unsigned short* __restrict__ dst,
                               int Kd, int Nd) {
    int e  = blockIdx.z;
    int n0 = blockIdx.x * 64;
    int k0 = blockIdx.y * 64;
    const float* s = src + (size_t)e * Kd * Nd;
    unsigned short* d = dst + (size_t)e * Kd * Nd;
    __shared__ float tile[64][65];
    int c  = threadIdx.x & 63;
    int r4 = threadIdx.x >> 6;
#pragma unroll
    for (int i = 0; i < 16; i++) {
        int r = r4 + i * 4;
        tile[r][c] = s[(size_t)(k0 + r) * Nd + n0 + c];
    }
    __syncthreads();
#pragma unroll
    for (int i = 0; i < 16; i++) {
        int r = r4 + i * 4;
        d[(size_t)(n0 + r) * Kd + k0 + c] = f2b(tile[c][r]);
    }
}

// ---------------- stats zero ----------------
__global__ void zero_stats(int* p) {
    if (threadIdx.x < 128) p[threadIdx.x] = 0;
}

// ---------------- gating (one token per wave) + fused x->bf16 convert ----------------
__global__ __launch_bounds__(256) void gating(const float* __restrict__ x, const float* __restrict__ wg,
                       const float* __restrict__ eps,
                       float* __restrict__ stats_f, int* __restrict__ stats_i,
                       int* __restrict__ top_i, float* __restrict__ top_g,
                       unsigned short* __restrict__ xb) {
    __shared__ float l_psum[8], l_gsum[8], l_zl;
    __shared__ int   l_cr[8], l_cp[8];
    int tid = threadIdx.x;
    if (tid < 8) { l_psum[tid] = 0.f; l_gsum[tid] = 0.f; l_cr[tid] = 0; l_cp[tid] = 0; }
    if (tid == 0) l_zl = 0.f;
    __syncthreads();
    int wave = tid >> 6, lane = tid & 63;
    int t = blockIdx.x * 4 + wave;
    const float* xr = x + (size_t)t * DD;
    unsigned short* xbr = xb + (size_t)t * DD;
    float acc[16];
#pragma unroll
    for (int j = 0; j < 16; j++) acc[j] = 0.f;
#pragma unroll
    for (int i = 0; i < 16; i++) {
        int dd = lane + i * 64;
        float xv = xr[dd];
        xbr[dd] = f2b(xv);
        const float4* wr = (const float4*)(wg + dd * 16);
        float4 w0 = wr[0], w1 = wr[1], w2 = wr[2], w3 = wr[3];
        acc[0]  += xv * w0.x; acc[1]  += xv * w0.y; acc[2]  += xv * w0.z; acc[3]  += xv * w0.w;
        acc[4]  += xv * w1.x; acc[5]  += xv * w1.y; acc[6]  += xv * w1.z; acc[7]  += xv * w1.w;
        acc[8]  += xv * w2.x; acc[9]  += xv * w2.y; acc[10] += xv * w2.z; acc[11] += xv * w2.w;
        acc[12] += xv * w3.x; acc[13] += xv * w3.y; acc[14] += xv * w3.z; acc[15] += xv * w3.w;
    }
#pragma unroll
    for (int j = 0; j < 16; j++)
#pragma unroll
        for (int o = 32; o > 0; o >>= 1) acc[j] += __shfl_xor(acc[j], o, 64);
    if (lane == 0) {
        float lg[8], p[8];
        float mx = -1e30f;
        for (int e2 = 0; e2 < 8; e2++) {
            float raw = acc[8 + e2];
            float sp = (raw > 20.f) ? raw : log1pf(__expf(raw));
            float l = acc[e2] + eps[(size_t)t * 8 + e2] * (sp + 0.01f);
            lg[e2] = l; mx = fmaxf(mx, l);
        }
        float se = 0.f;
        for (int e2 = 0; e2 < 8; e2++) { p[e2] = __expf(lg[e2] - mx); se += p[e2]; }
        float lse = mx + logf(se);
        float inv = 1.f / se;
        for (int e2 = 0; e2 < 8; e2++) p[e2] *= inv;
        int i0 = 0;
        for (int e2 = 1; e2 < 8; e2++) if (p[e2] > p[i0]) i0 = e2;
        int i1 = (i0 == 0) ? 1 : 0;
        for (int e2 = 0; e2 < 8; e2++) if (e2 != i0 && p[e2] > p[i1]) i1 = e2;
        float g0 = p[i0], g1 = p[i1];
        top_i[t * 2] = i0; top_i[t * 2 + 1] = i1;
        top_g[t * 2] = g0; top_g[t * 2 + 1] = g1;
        for (int e2 = 0; e2 < 8; e2++) atomicAdd(&l_psum[e2], p[e2]);
        atomicAdd(&l_gsum[i0], g0); atomicAdd(&l_gsum[i1], g1);
        atomicAdd(&l_zl, lse * lse);
        atomicAdd(&l_cr[i0], 1); atomicAdd(&l_cr[i1], 1);
        if (g0 > 0.f) atomicAdd(&l_cp[i0], 1);
        if (g1 > 0.f) atomicAdd(&l_cp[i1], 1);
    }
    __syncthreads();
    if (tid < 8) {
        atomicAdd(&stats_f[tid],      l_psum[tid]);
        atomicAdd(&stats_f[8 + tid],  l_gsum[tid]);
        atomicAdd(&stats_i[tid],      l_cr[tid]);
        atomicAdd(&stats_i[8 + tid],  l_cp[tid]);
    }
    if (tid == 0) atomicAdd(&stats_f[16], l_zl);
}

// ---------------- offsets + loss ----------------
__global__ void offsets_loss(const float* __restrict__ stats_f, int* __restrict__ stats_i,
                             float* __restrict__ loss_out) {
    if (threadIdx.x != 0) return;
    int off = 0;
    for (int e = 0; e < 8; e++) { stats_i[24 + e] = off; off += stats_i[e]; }
    stats_i[32] = off;
    float gs = 0.f;
    for (int e = 0; e < 8; e++) gs += stats_f[8 + e];
    float var = 0.f;
    for (int e = 0; e < 8; e++) {
        float gn = stats_f[8 + e] / gs;
        float d = gn - 0.125f;
        var += d * d;
    }
    var /= 7.f;
    float cv = var / (0.015625f + 1e-10f);
    float ps = 0.f, cs = 0.f;
    for (int e = 0; e < 8; e++) { ps += stats_f[e]; cs += (float)stats_i[8 + e]; }
    float dot = 0.f;
    for (int e = 0; e < 8; e++) dot += (stats_f[e] / ps) * ((float)stats_i[8 + e] / cs);
    float sw = (1.f - dot) * 8.f;
    float zl = stats_f[16] / (float)TT;
    *loss_out = 0.01f * cv + 0.1f * sw + 0.0001f * zl;
}

// ---------------- scatter pairs ----------------
__global__ void scatter(const int* __restrict__ top_i, int* __restrict__ stats_i,
                        int* __restrict__ row_token, int* __restrict__ pair_pos) {
    __shared__ int lcnt[8], lbase[8];
    int tid = threadIdx.x;
    if (tid < 8) lcnt[tid] = 0;
    __syncthreads();
    int t = blockIdx.x * 256 + tid;
    int e0 = top_i[t * 2], e1 = top_i[t * 2 + 1];
    int p0 = atomicAdd(&lcnt[e0], 1);
    int p1 = atomicAdd(&lcnt[e1], 1);
    __syncthreads();
    if (tid < 8) lbase[tid] = atomicAdd(&stats_i[16 + tid], lcnt[tid]);
    __syncthreads();
    const int* offs = stats_i + 24;
    int idx0 = offs[e0] + lbase[e0] + p0;
    int idx1 = offs[e1] + lbase[e1] + p1;
    row_token[idx0] = t;
    row_token[idx1] = t;
    pair_pos[t * 2] = idx0;
    pair_pos[t * 2 + 1] = idx1;
}

// ============ grouped GEMM, persistent blocks + atomic tile queue, 256x256 tile, 8-phase ============
// 8 waves (2M x 4N), per-wave output 128x64. 2 K-tiles/iter, 4 phases each (quadrant = 16 MFMA).
// Tile list (device-derived): expert-major, tile t -> (e, rt = local>>3, q = local&7);
// tiles per expert = ceil(ne/256) * 8. q -> n0 = (q%NTILES)*256, split = q/NTILES.
// vmcnt(6) at phases 4/8 only (3 chunk-pairs in flight). Stage ledger identical to R5 (verified).
template<int KTOT, int KSPLITS, int NTILES, bool GATHER, bool RELU>
__global__ __launch_bounds__(512, 1) void gemm8p(
    const unsigned short* __restrict__ A,
    const unsigned short* __restrict__ Bt,
    unsigned short* __restrict__ C, long long split_stride,
    const int* __restrict__ row_token, const int* __restrict__ stats_i,
    int* __restrict__ ctr) {
    constexpr int KD   = KTOT / KSPLITS;   // K handled per block
    constexpr int NK   = KD / 64;          // K-tiles
    constexpr int NI   = NK / 2;           // iterations (2 K-tiles each)
    constexpr int NDIM = NTILES * 256;
    static_assert(NTILES * KSPLITS == 8, "q must span 8");
    static_assert(NI >= 2, "need >=4 K-tiles");

    __shared__ __align__(16) unsigned short Al[2][256 * 64];
    __shared__ __align__(16) unsigned short Bl[2][256 * 64];
    __shared__ int sh_t;

    const int* offs = stats_i + 24;
    int tid = threadIdx.x;
    int lane = tid & 63, wave = tid >> 6;
    int wm = wave >> 2, wn = wave & 3;

    for (;;) {
        if (tid == 0) sh_t = atomicAdd(ctr, 1);
        __syncthreads();
        int t = sh_t;
        // map t -> (expert, local) via 8-entry scan
        int eE = -1, local = 0, base = 0;
#pragma unroll
        for (int e = 0; e < 8; e++) {
            int ne_ = offs[e + 1] - offs[e];
            int cnt = ((ne_ + 255) >> 8) * 8;
            if (eE < 0 && t < base + cnt) { eE = e; local = t - base; }
            base += cnt;
        }
        if (t >= base) break;          // queue drained (uniform: t uniform per block)
        int off = offs[eE];
        int ne  = offs[eE + 1] - off;
        int q4  = local & 7;
        int rt  = local >> 3;
        int n0  = (q4 % NTILES) * 256;
        int split = q4 / NTILES;

        // staging source pointers (XOR-pre-swizzled; pairs with swizzled ds_read)
        const unsigned short* Asrc[4];
#pragma unroll
        for (int i = 0; i < 4; i++) {
            int glin = i * 512 + tid;
            int row = glin >> 3, sl = glin & 7, g = sl ^ (row & 7);
            int arow;
            if (GATHER) arow = row_token[min(off + rt * 256 + row, TK - 1)];
            else        arow = min(off + rt * 256 + row, TK - 1);
            Asrc[i] = A + (size_t)arow * KTOT + split * KD + g * 8;
        }
        const unsigned short* Bte = Bt + (size_t)eE * NDIM * KTOT;
        const unsigned short* Bsrc[4];
#pragma unroll
        for (int i = 0; i < 4; i++) {
            int glin = i * 512 + tid;
            int row = glin >> 3, sl = glin & 7, g = sl ^ (row & 7);
            Bsrc[i] = Bte + (size_t)(n0 + row) * KTOT + split * KD + g * 8;
        }

        f32x4 acc[8][4];
#pragma unroll
        for (int m = 0; m < 8; m++)
#pragma unroll
            for (int n = 0; n < 4; n++)
#pragma unroll
                for (int i = 0; i < 4; i++) acc[m][n][i] = 0.f;

        bf16x8 bv[2][4], av[2][2];

#define STG_A(SLOT, KT, CC) GLOAD_LDS16(Asrc[CC] + (KT) * 64, &Al[SLOT][(CC) * 4096 + wave * 512])
#define STG_B(SLOT, KT, CC) GLOAD_LDS16(Bsrc[CC] + (KT) * 64, &Bl[SLOT][(CC) * 4096 + wave * 512])

#define LOAD_B(SLOT) do { \
    _Pragma("unroll") for (int kk2 = 0; kk2 < 2; kk2++) \
    _Pragma("unroll") for (int n = 0; n < 4; n++) { \
        int row = wn * 64 + n * 16 + (lane & 15); \
        int g = (kk2 * 4 + (lane >> 4)) ^ (row & 7); \
        bv[kk2][n] = *(const bf16x8*)(&Bl[SLOT][row * 64 + g * 8]); \
    } } while (0)

#define LOAD_AQ(SLOT, QQ) do { \
    _Pragma("unroll") for (int kk2 = 0; kk2 < 2; kk2++) \
    _Pragma("unroll") for (int mi = 0; mi < 2; mi++) { \
        int row = wm * 128 + (QQ) * 32 + mi * 16 + (lane & 15); \
        int g = (kk2 * 4 + (lane >> 4)) ^ (row & 7); \
        av[kk2][mi] = *(const bf16x8*)(&Al[SLOT][row * 64 + g * 8]); \
    } } while (0)

#define MFMA_Q(QQ) do { \
    _Pragma("unroll") for (int kk2 = 0; kk2 < 2; kk2++) \
    _Pragma("unroll") for (int mi = 0; mi < 2; mi++) \
    _Pragma("unroll") for (int n = 0; n < 4; n++) \
        acc[(QQ) * 2 + mi][n] = __builtin_amdgcn_mfma_f32_16x16x32_bf16(av[kk2][mi], bv[kk2][n], acc[(QQ) * 2 + mi][n], 0, 0, 0); \
    } while (0)

#define PHASE(SLOT, QQ, STAGE_STMT, WAIT_STMT) do { \
    if ((QQ) == 0) LOAD_B(SLOT); \
    LOAD_AQ(SLOT, QQ); \
    STAGE_STMT; \
    __builtin_amdgcn_s_barrier(); \
    asm volatile("s_waitcnt lgkmcnt(0)" ::: "memory"); \
    __builtin_amdgcn_s_setprio(1); \
    MFMA_Q(QQ); \
    __builtin_amdgcn_s_setprio(0); \
    WAIT_STMT; \
    __builtin_amdgcn_s_barrier(); \
    } while (0)

        // prologue: K0 fully -> slot0; K1 all but {A1,A3} -> slot1 (14 loads; wait oldest 8)
#pragma unroll
        for (int c = 0; c < 4; c++) STG_B(0, 0, c);
#pragma unroll
        for (int c = 0; c < 4; c++) STG_A(0, 0, c);
#pragma unroll
        for (int c = 0; c < 4; c++) STG_B(1, 1, c);
        STG_A(1, 1, 0); STG_A(1, 1, 2);
        asm volatile("s_waitcnt vmcnt(6)" ::: "memory");
        __builtin_amdgcn_s_barrier();

#pragma unroll 1
        for (int it = 0; it < NI; ++it) {
            int u = 2 * it, v = u + 1;
            bool ns = (it + 1 < NI);
            PHASE(0, 0, { STG_A(1, v, 1); STG_A(1, v, 3); }, {});
            PHASE(0, 1, { if (ns) { STG_B(0, u + 2, 0); STG_B(0, u + 2, 1); } }, {});
            PHASE(0, 2, { if (ns) { STG_B(0, u + 2, 2); STG_B(0, u + 2, 3); } }, {});
            PHASE(0, 3, { if (ns) { STG_A(0, u + 2, 0); STG_A(0, u + 2, 2); } },
                        { if (ns) asm volatile("s_waitcnt vmcnt(6)" ::: "memory");
                          else    asm volatile("s_waitcnt vmcnt(0)" ::: "memory"); });
            PHASE(1, 0, { if (ns) { STG_A(0, u + 2, 1); STG_A(0, u + 2, 3); } }, {});
            PHASE(1, 1, { if (ns) { STG_B(1, v + 2, 0); STG_B(1, v + 2, 1); } }, {});
            PHASE(1, 2, { if (ns) { STG_B(1, v + 2, 2); STG_B(1, v + 2, 3); } }, {});
            PHASE(1, 3, { if (ns) { STG_A(1, v + 2, 0); STG_A(1, v + 2, 2); } },
                        { if (ns) asm volatile("s_waitcnt vmcnt(6)" ::: "memory"); });
        }
#undef PHASE
#undef MFMA_Q
#undef LOAD_AQ
#undef LOAD_B
#undef STG_A
#undef STG_B

        // epilogue
        unsigned short* Cb = C + (ptrdiff_t)split * split_stride;
#pragma unroll
        for (int m = 0; m < 8; m++) {
            int rr0 = rt * 256 + wm * 128 + m * 16 + (lane >> 4) * 4;
#pragma unroll
            for (int i = 0; i < 4; i++) {
                if (rr0 + i < ne) {
                    size_t grow = (size_t)(off + rr0 + i);
#pragma unroll
                    for (int n = 0; n < 4; n++) {
                        int col = n0 + wn * 64 + n * 16 + (lane & 15);
                        float vvv = acc[m][n][i];
                        if (RELU) vvv = fmaxf(vvv, 0.f);
                        Cb[grow * NDIM + col] = f2b(vvv);
                    }
                }
            }
        }
        __syncthreads();   // all waves done with LDS + sh_t before next grab
    }
}

// ---------------- gated combine (sums the two GEMM2 K-splits) ----------------
__global__ void combine(const unsigned short* __restrict__ o0,
                        const unsigned short* __restrict__ o1,
                        const int* __restrict__ pair_pos, const float* __restrict__ top_g,
                        float* __restrict__ y) {
    int t = blockIdx.x;
    int tid = threadIdx.x;
    int i0 = pair_pos[t * 2], i1 = pair_pos[t * 2 + 1];
    float g0 = top_g[t * 2], g1 = top_g[t * 2 + 1];
    int d0 = tid * 4;
    ushort4 a0 = *(const ushort4*)(o0 + (size_t)i0 * DD + d0);
    ushort4 a1 = *(const ushort4*)(o1 + (size_t)i0 * DD + d0);
    ushort4 b0 = *(const ushort4*)(o0 + (size_t)i1 * DD + d0);
    ushort4 b1 = *(const ushort4*)(o1 + (size_t)i1 * DD + d0);
    float4 o;
    o.x = g0 * (b2f(a0.x) + b2f(a1.x)) + g1 * (b2f(b0.x) + b2f(b1.x));
    o.y = g0 * (b2f(a0.y) + b2f(a1.y)) + g1 * (b2f(b0.y) + b2f(b1.y));
    o.z = g0 * (b2f(a0.z) + b2f(a1.z)) + g1 * (b2f(b0.z) + b2f(b1.z));
    o.w = g0 * (b2f(a0.w) + b2f(a1.w)) + g1 * (b2f(b0.w) + b2f(b1.w));
    *(float4*)(y + (size_t)t * DD + d0) = o;
}

extern "C" void kernel_launch(void* const* d_in, const int* in_sizes, int n_in,
                              void* d_out, int out_size, void* d_ws, size_t ws_size,
                              hipStream_t stream) {
    const float* x   = (const float*)d_in[0];
    const float* wg  = (const float*)d_in[1];
    const float* w1  = (const float*)d_in[2];
    const float* w2  = (const float*)d_in[3];
    const float* eps = (const float*)d_in[4];
    float* y = (float*)d_out;
    char* ws = (char*)d_ws;

    unsigned short* xb    = (unsigned short*)(ws);                 //  8 MB
    unsigned short* w1bT  = (unsigned short*)(ws + 8388608);       // 32 MB  [E][H][D]
    unsigned short* w2bT  = (unsigned short*)(ws + 41943040);      // 32 MB  [E][D][H]
    unsigned short* hbuf  = (unsigned short*)(ws + 75497472);      // 32 MB  [TK][H]
    unsigned short* outp0 = (unsigned short*)(ws + 109051904);     // 16 MB  [TK][D] split 0
    unsigned short* outp1 = (unsigned short*)(ws + 8388608);       // 16 MB  split 1 (reuses w1bT, dead after GEMM1)
    int*   top_i    = (int*)(ws + 125829120);
    float* top_g    = (float*)(ws + 125861888);
    int*   row_token= (int*)(ws + 125894656);
    int*   pair_pos = (int*)(ws + 125927424);
    float* stats_f  = (float*)(ws + 125960192);
    int*   stats_i  = (int*)(ws + 125960192 + 128);

    zero_stats<<<1, 128, 0, stream>>>((int*)(ws + 125960192));
    conv_transpose<<<dim3(32, 16, 8), 256, 0, stream>>>(w1, w1bT, 1024, 2048);
    conv_transpose<<<dim3(16, 32, 8), 256, 0, stream>>>(w2, w2bT, 2048, 1024);
    gating<<<1024, 256, 0, stream>>>(x, wg, eps, stats_f, stats_i, top_i, top_g, xb);
    offsets_loss<<<1, 64, 0, stream>>>(stats_f, stats_i, y + (size_t)TT * DD);
    scatter<<<16, 256, 0, stream>>>(top_i, stats_i, row_token, pair_pos);
    // GEMM1: [pairs,1024] x [2048,1024]^T -> hbuf [pairs,2048], relu, gathered A
    gemm8p<1024, 1, 8, true,  true ><<<256, 512, 0, stream>>>(
        xb, w1bT, hbuf, 0, row_token, stats_i, &stats_i[33]);
    // GEMM2: [pairs,2048] x [1024,2048]^T -> outp [pairs,1024], split-K=2
    gemm8p<2048, 2, 4, false, false><<<256, 512, 0, stream>>>(
        hbuf, w2bT, outp0, (long long)(outp1 - outp0), row_token, stats_i, &stats_i[34]);
    combine<<<4096, 256, 0, stream>>>(outp0, outp1, pair_pos, top_g, y);
}

// Round 8
// 215.626 us; speedup vs baseline: 1.1010x; 1.1010x over previous
//
#include <hip/hip_runtime.h>

// Problem constants
#define TT 4096      // tokens (B*L)
#define DD 1024      // model dim
#define HH 2048      // hidden dim
#define EE 8         // experts
#define TK 8192      // T*K pairs (K=2)

typedef short  bf16x8 __attribute__((ext_vector_type(8)));
typedef float  f32x4  __attribute__((ext_vector_type(4)));

__device__ __forceinline__ unsigned short f2b(float f) {
    unsigned int u = __float_as_uint(f);
    unsigned int r = (u + 0x7fffu + ((u >> 16) & 1u)) >> 16;  // RNE
    return (unsigned short)r;
}
__device__ __forceinline__ float b2f(unsigned short b) {
    return __uint_as_float(((unsigned int)b) << 16);
}

#define GLOAD_LDS16(SRC, DST) __builtin_amdgcn_global_load_lds( \
    (const __attribute__((address_space(1))) unsigned int*)(SRC), \
    (__attribute__((address_space(3))) unsigned int*)(DST), 16, 0, 0)

// ------------- weight transpose + bf16 convert: src [E][Kd][Nd] -> dst [E][Nd][Kd] -------------
__global__ void conv_transpose(const float* __restrict__ src, unsigned short* __restrict__ dst,
                               int Kd, int Nd) {
    int e  = blockIdx.z;
    int n0 = blockIdx.x * 64;
    int k0 = blockIdx.y * 64;
    const float* s = src + (size_t)e * Kd * Nd;
    unsigned short* d = dst + (size_t)e * Kd * Nd;
    __shared__ float tile[64][65];
    int c  = threadIdx.x & 63;
    int r4 = threadIdx.x >> 6;
#pragma unroll
    for (int i = 0; i < 16; i++) {
        int r = r4 + i * 4;
        tile[r][c] = s[(size_t)(k0 + r) * Nd + n0 + c];
    }
    __syncthreads();
#pragma unroll
    for (int i = 0; i < 16; i++) {
        int r = r4 + i * 4;
        d[(size_t)(n0 + r) * Kd + k0 + c] = f2b(tile[c][r]);
    }
}

// ---------------- stats zero ----------------
__global__ void zero_stats(int* p) {
    if (threadIdx.x < 192) p[threadIdx.x] = 0;
}

// ---------------- gating (one token per wave) + fused x->bf16 convert ----------------
__global__ __launch_bounds__(256) void gating(const float* __restrict__ x, const float* __restrict__ wg,
                       const float* __restrict__ eps,
                       float* __restrict__ stats_f, int* __restrict__ stats_i,
                       int* __restrict__ top_i, float* __restrict__ top_g,
                       unsigned short* __restrict__ xb) {
    __shared__ float l_psum[8], l_gsum[8], l_zl;
    __shared__ int   l_cr[8], l_cp[8];
    int tid = threadIdx.x;
    if (tid < 8) { l_psum[tid] = 0.f; l_gsum[tid] = 0.f; l_cr[tid] = 0; l_cp[tid] = 0; }
    if (tid == 0) l_zl = 0.f;
    __syncthreads();
    int wave = tid >> 6, lane = tid & 63;
    int t = blockIdx.x * 4 + wave;
    const float* xr = x + (size_t)t * DD;
    unsigned short* xbr = xb + (size_t)t * DD;
    float acc[16];
#pragma unroll
    for (int j = 0; j < 16; j++) acc[j] = 0.f;
#pragma unroll
    for (int i = 0; i < 16; i++) {
        int dd = lane + i * 64;
        float xv = xr[dd];
        xbr[dd] = f2b(xv);
        const float4* wr = (const float4*)(wg + dd * 16);
        float4 w0 = wr[0], w1 = wr[1], w2 = wr[2], w3 = wr[3];
        acc[0]  += xv * w0.x; acc[1]  += xv * w0.y; acc[2]  += xv * w0.z; acc[3]  += xv * w0.w;
        acc[4]  += xv * w1.x; acc[5]  += xv * w1.y; acc[6]  += xv * w1.z; acc[7]  += xv * w1.w;
        acc[8]  += xv * w2.x; acc[9]  += xv * w2.y; acc[10] += xv * w2.z; acc[11] += xv * w2.w;
        acc[12] += xv * w3.x; acc[13] += xv * w3.y; acc[14] += xv * w3.z; acc[15] += xv * w3.w;
    }
#pragma unroll
    for (int j = 0; j < 16; j++)
#pragma unroll
        for (int o = 32; o > 0; o >>= 1) acc[j] += __shfl_xor(acc[j], o, 64);
    if (lane == 0) {
        float lg[8], p[8];
        float mx = -1e30f;
        for (int e2 = 0; e2 < 8; e2++) {
            float raw = acc[8 + e2];
            float sp = (raw > 20.f) ? raw : log1pf(__expf(raw));
            float l = acc[e2] + eps[(size_t)t * 8 + e2] * (sp + 0.01f);
            lg[e2] = l; mx = fmaxf(mx, l);
        }
        float se = 0.f;
        for (int e2 = 0; e2 < 8; e2++) { p[e2] = __expf(lg[e2] - mx); se += p[e2]; }
        float lse = mx + logf(se);
        float inv = 1.f / se;
        for (int e2 = 0; e2 < 8; e2++) p[e2] *= inv;
        int i0 = 0;
        for (int e2 = 1; e2 < 8; e2++) if (p[e2] > p[i0]) i0 = e2;
        int i1 = (i0 == 0) ? 1 : 0;
        for (int e2 = 0; e2 < 8; e2++) if (e2 != i0 && p[e2] > p[i1]) i1 = e2;
        float g0 = p[i0], g1 = p[i1];
        top_i[t * 2] = i0; top_i[t * 2 + 1] = i1;
        top_g[t * 2] = g0; top_g[t * 2 + 1] = g1;
        for (int e2 = 0; e2 < 8; e2++) atomicAdd(&l_psum[e2], p[e2]);
        atomicAdd(&l_gsum[i0], g0); atomicAdd(&l_gsum[i1], g1);
        atomicAdd(&l_zl, lse * lse);
        atomicAdd(&l_cr[i0], 1); atomicAdd(&l_cr[i1], 1);
        if (g0 > 0.f) atomicAdd(&l_cp[i0], 1);
        if (g1 > 0.f) atomicAdd(&l_cp[i1], 1);
    }
    __syncthreads();
    if (tid < 8) {
        atomicAdd(&stats_f[tid],      l_psum[tid]);
        atomicAdd(&stats_f[8 + tid],  l_gsum[tid]);
        atomicAdd(&stats_i[tid],      l_cr[tid]);
        atomicAdd(&stats_i[8 + tid],  l_cp[tid]);
    }
    if (tid == 0) atomicAdd(&stats_f[16], l_zl);
}

// ---------------- offsets + loss ----------------
__global__ void offsets_loss(const float* __restrict__ stats_f, int* __restrict__ stats_i,
                             float* __restrict__ loss_out) {
    if (threadIdx.x != 0) return;
    int off = 0;
    for (int e = 0; e < 8; e++) { stats_i[24 + e] = off; off += stats_i[e]; }
    stats_i[32] = off;
    float gs = 0.f;
    for (int e = 0; e < 8; e++) gs += stats_f[8 + e];
    float var = 0.f;
    for (int e = 0; e < 8; e++) {
        float gn = stats_f[8 + e] / gs;
        float d = gn - 0.125f;
        var += d * d;
    }
    var /= 7.f;
    float cv = var / (0.015625f + 1e-10f);
    float ps = 0.f, cs = 0.f;
    for (int e = 0; e < 8; e++) { ps += stats_f[e]; cs += (float)stats_i[8 + e]; }
    float dot = 0.f;
    for (int e = 0; e < 8; e++) dot += (stats_f[e] / ps) * ((float)stats_i[8 + e] / cs);
    float sw = (1.f - dot) * 8.f;
    float zl = stats_f[16] / (float)TT;
    *loss_out = 0.01f * cv + 0.1f * sw + 0.0001f * zl;
}

// ---------------- scatter pairs ----------------
__global__ void scatter(const int* __restrict__ top_i, int* __restrict__ stats_i,
                        int* __restrict__ row_token, int* __restrict__ pair_pos) {
    __shared__ int lcnt[8], lbase[8];
    int tid = threadIdx.x;
    if (tid < 8) lcnt[tid] = 0;
    __syncthreads();
    int t = blockIdx.x * 256 + tid;
    int e0 = top_i[t * 2], e1 = top_i[t * 2 + 1];
    int p0 = atomicAdd(&lcnt[e0], 1);
    int p1 = atomicAdd(&lcnt[e1], 1);
    __syncthreads();
    if (tid < 8) lbase[tid] = atomicAdd(&stats_i[16 + tid], lcnt[tid]);
    __syncthreads();
    const int* offs = stats_i + 24;
    int idx0 = offs[e0] + lbase[e0] + p0;
    int idx1 = offs[e1] + lbase[e1] + p1;
    row_token[idx0] = t;
    row_token[idx1] = t;
    pair_pos[t * 2] = idx0;
    pair_pos[t * 2 + 1] = idx1;
}

// ============ grouped GEMM, 320x256 tile, BK=64, 8-phase, static grid (1 round) ============
// Tiles per expert: ceil(ne/320) <= 5 (provisioned; slot rt=4 dispatched LAST, usually empty).
// 8 waves as 4M x 2N: per-wave 80x128 output (5 m-frags x 8 n-frags). 2 K-tiles/iter; per
// K-tile 4 phases over n-frag pairs; per phase: 20 MFMA (5m x 2n x 2kk).
// Chunks/K-tile: A=5 (64 rows each), B=4. Ledger (slot0=u, slot1=v=u+1):
//   ph0: B(v){1,3}            [finishes K v]
//   ph1: A(u+2){0,1,2}        [slot0 A free after ph0]
//   ph2: A(u+2){3,4}, B(u+2){0,2}   [B chunks 0,2 last read ph1]
//   ph3: -- wait vmcnt(7)     [K v fully landed: 7 = ph1(3)+ph2(4) outstanding]
//   ph4: B(u+2){1,3}          [slot0 B chunks 1,3 free after ph3]
//   ph5: A(v+2){0,1,2}
//   ph6: A(v+2){3,4}, B(v+2){0,2}
//   ph7: -- wait vmcnt(7)     [K u+2 fully landed: 7 = ph5(3)+ph6(4)]
// Intra-phase stage/read disjointness verified per chunk (see derivation); per-thread chunk = 1
// global_load_lds instr. Prologue: K0 full (9) + K1 {A0-4,B0,B2} (7) -> vmcnt(7).
template<int KTOT, int KSPLITS, int NTILES, bool GATHER, bool RELU>
__global__ __launch_bounds__(512, 2) void gemm320(
    const unsigned short* __restrict__ A,
    const unsigned short* __restrict__ Bt,
    unsigned short* __restrict__ C, long long split_stride,
    const int* __restrict__ row_token, const int* __restrict__ stats_i) {
    constexpr int KD   = KTOT / KSPLITS;   // K per block (1024)
    constexpr int NK   = KD / 64;          // 16
    constexpr int NI   = NK / 2;           // 8
    constexpr int NDIM = NTILES * 256;
    static_assert(NTILES * KSPLITS == 8, "q must span 8");
    static_assert(NI >= 2, "need >=4 K-tiles");

    int lin = blockIdx.x;
    int e   = lin & 7;                     // expert pinned to XCD
    int rem = lin >> 3;                    // 0..39
    int q   = rem & 7;
    int rt  = rem >> 3;                    // 0..4 ; rt=4 <=> lin>=256 (dispatched last)
    int n0  = (q % NTILES) * 256;
    int split = q / NTILES;

    const int* offs = stats_i + 24;
    int off = offs[e];
    int ne  = offs[e + 1] - off;
    if (rt * 320 >= ne) return;

    __shared__ __align__(16) unsigned short Al[2 * 320 * 64];   // 80 KB (slot=20480 shorts)
    __shared__ __align__(16) unsigned short Bl[2 * 256 * 64];   // 64 KB (slot=16384 shorts)

    int tid = threadIdx.x;
    int lane = tid & 63, wave = tid >> 6;
    int wm = wave >> 1, wn = wave & 1;     // 4M x 2N

    // staging source pointers (XOR-pre-swizzled; pairs with swizzled ds_read)
    const unsigned short* Asrc[5];
#pragma unroll
    for (int i = 0; i < 5; i++) {
        int glin = i * 512 + tid, row = glin >> 3, sl = glin & 7, g = sl ^ (row & 7);
        int arow;
        if (GATHER) arow = row_token[min(off + rt * 320 + row, TK - 1)];
        else        arow = min(off + rt * 320 + row, TK - 1);
        Asrc[i] = A + (size_t)arow * KTOT + split * KD + g * 8;
    }
    const unsigned short* Bte = Bt + (size_t)e * NDIM * KTOT;
    const unsigned short* Bsrc[4];
#pragma unroll
    for (int i = 0; i < 4; i++) {
        int glin = i * 512 + tid, row = glin >> 3, sl = glin & 7, g = sl ^ (row & 7);
        Bsrc[i] = Bte + (size_t)(n0 + row) * KTOT + split * KD + g * 8;
    }

    f32x4 acc[5][8];
#pragma unroll
    for (int m = 0; m < 5; m++)
#pragma unroll
        for (int n = 0; n < 8; n++)
#pragma unroll
            for (int i = 0; i < 4; i++) acc[m][n][i] = 0.f;

    bf16x8 av[2][5], bv[2][2];

#define STG_A(SLOT, KT, CC) GLOAD_LDS16(Asrc[CC] + (KT) * 64, Al + (SLOT) * 20480 + (CC) * 4096 + wave * 512)
#define STG_B(SLOT, KT, CC) GLOAD_LDS16(Bsrc[CC] + (KT) * 64, Bl + (SLOT) * 16384 + (CC) * 4096 + wave * 512)

#define LOAD_A(SLOT) do { \
    _Pragma("unroll") for (int kk2 = 0; kk2 < 2; kk2++) \
    _Pragma("unroll") for (int mi = 0; mi < 5; mi++) { \
        int row = wm * 80 + mi * 16 + (lane & 15); \
        int g = (kk2 * 4 + (lane >> 4)) ^ (row & 7); \
        av[kk2][mi] = *(const bf16x8*)(Al + (SLOT) * 20480 + row * 64 + g * 8); \
    } } while (0)

#define LOAD_B(SLOT, QQ) do { \
    _Pragma("unroll") for (int kk2 = 0; kk2 < 2; kk2++) \
    _Pragma("unroll") for (int j = 0; j < 2; j++) { \
        int row = wn * 128 + ((QQ) * 2 + j) * 16 + (lane & 15); \
        int g = (kk2 * 4 + (lane >> 4)) ^ (row & 7); \
        bv[kk2][j] = *(const bf16x8*)(Bl + (SLOT) * 16384 + row * 64 + g * 8); \
    } } while (0)

#define MFMA_Q(QQ) do { \
    _Pragma("unroll") for (int kk2 = 0; kk2 < 2; kk2++) \
    _Pragma("unroll") for (int mi = 0; mi < 5; mi++) \
    _Pragma("unroll") for (int j = 0; j < 2; j++) \
        acc[mi][(QQ) * 2 + j] = __builtin_amdgcn_mfma_f32_16x16x32_bf16(av[kk2][mi], bv[kk2][j], acc[mi][(QQ) * 2 + j], 0, 0, 0); \
    } while (0)

#define PHASE(SLOT, QQ, STAGE_STMT, WAIT_STMT) do { \
    if ((QQ) == 0) LOAD_A(SLOT); \
    LOAD_B(SLOT, QQ); \
    STAGE_STMT; \
    __builtin_amdgcn_s_barrier(); \
    asm volatile("s_waitcnt lgkmcnt(0)" ::: "memory"); \
    __builtin_amdgcn_s_setprio(1); \
    MFMA_Q(QQ); \
    __builtin_amdgcn_s_setprio(0); \
    WAIT_STMT; \
    __builtin_amdgcn_s_barrier(); \
    } while (0)

    // prologue: K0 full (9) -> slot0; K1 {A0..4, B0, B2} (7) -> slot1; wait oldest 9
#pragma unroll
    for (int c = 0; c < 5; c++) STG_A(0, 0, c);
#pragma unroll
    for (int c = 0; c < 4; c++) STG_B(0, 0, c);
#pragma unroll
    for (int c = 0; c < 5; c++) STG_A(1, 1, c);
    STG_B(1, 1, 0); STG_B(1, 1, 2);
    asm volatile("s_waitcnt vmcnt(7)" ::: "memory");
    __builtin_amdgcn_s_barrier();

#pragma unroll 1
    for (int it = 0; it < NI; ++it) {
        int u = 2 * it, v = u + 1;
        bool ns = (it + 1 < NI);
        PHASE(0, 0, { STG_B(1, v, 1); STG_B(1, v, 3); }, {});
        PHASE(0, 1, { if (ns) { STG_A(0, u + 2, 0); STG_A(0, u + 2, 1); STG_A(0, u + 2, 2); } }, {});
        PHASE(0, 2, { if (ns) { STG_A(0, u + 2, 3); STG_A(0, u + 2, 4);
                                STG_B(0, u + 2, 0); STG_B(0, u + 2, 2); } }, {});
        PHASE(0, 3, {}, { if (ns) asm volatile("s_waitcnt vmcnt(7)" ::: "memory");
                          else    asm volatile("s_waitcnt vmcnt(0)" ::: "memory"); });
        PHASE(1, 0, { if (ns) { STG_B(0, u + 2, 1); STG_B(0, u + 2, 3); } }, {});
        PHASE(1, 1, { if (ns) { STG_A(1, v + 2, 0); STG_A(1, v + 2, 1); STG_A(1, v + 2, 2); } }, {});
        PHASE(1, 2, { if (ns) { STG_A(1, v + 2, 3); STG_A(1, v + 2, 4);
                                STG_B(1, v + 2, 0); STG_B(1, v + 2, 2); } }, {});
        PHASE(1, 3, {}, { if (ns) asm volatile("s_waitcnt vmcnt(7)" ::: "memory"); });
    }
#undef PHASE
#undef MFMA_Q
#undef LOAD_B
#undef LOAD_A
#undef STG_A
#undef STG_B

    // epilogue
    unsigned short* Cb = C + (ptrdiff_t)split * split_stride;
#pragma unroll
    for (int m = 0; m < 5; m++) {
        int rr0 = rt * 320 + wm * 80 + m * 16 + (lane >> 4) * 4;
#pragma unroll
        for (int i = 0; i < 4; i++) {
            if (rr0 + i < ne) {
                size_t grow = (size_t)(off + rr0 + i);
#pragma unroll
                for (int n = 0; n < 8; n++) {
                    int col = n0 + wn * 128 + n * 16 + (lane & 15);
                    float vvv = acc[m][n][i];
                    if (RELU) vvv = fmaxf(vvv, 0.f);
                    Cb[grow * NDIM + col] = f2b(vvv);
                }
            }
        }
    }
}

// ---------------- gated combine (sums the two GEMM2 K-splits) ----------------
__global__ void combine(const unsigned short* __restrict__ o0,
                        const unsigned short* __restrict__ o1,
                        const int* __restrict__ pair_pos, const float* __restrict__ top_g,
                        float* __restrict__ y) {
    int t = blockIdx.x;
    int tid = threadIdx.x;
    int i0 = pair_pos[t * 2], i1 = pair_pos[t * 2 + 1];
    float g0 = top_g[t * 2], g1 = top_g[t * 2 + 1];
    int d0 = tid * 4;
    ushort4 a0 = *(const ushort4*)(o0 + (size_t)i0 * DD + d0);
    ushort4 a1 = *(const ushort4*)(o1 + (size_t)i0 * DD + d0);
    ushort4 b0 = *(const ushort4*)(o0 + (size_t)i1 * DD + d0);
    ushort4 b1 = *(const ushort4*)(o1 + (size_t)i1 * DD + d0);
    float4 o;
    o.x = g0 * (b2f(a0.x) + b2f(a1.x)) + g1 * (b2f(b0.x) + b2f(b1.x));
    o.y = g0 * (b2f(a0.y) + b2f(a1.y)) + g1 * (b2f(b0.y) + b2f(b1.y));
    o.z = g0 * (b2f(a0.z) + b2f(a1.z)) + g1 * (b2f(b0.z) + b2f(b1.z));
    o.w = g0 * (b2f(a0.w) + b2f(a1.w)) + g1 * (b2f(b0.w) + b2f(b1.w));
    *(float4*)(y + (size_t)t * DD + d0) = o;
}

extern "C" void kernel_launch(void* const* d_in, const int* in_sizes, int n_in,
                              void* d_out, int out_size, void* d_ws, size_t ws_size,
                              hipStream_t stream) {
    const float* x   = (const float*)d_in[0];
    const float* wg  = (const float*)d_in[1];
    const float* w1  = (const float*)d_in[2];
    const float* w2  = (const float*)d_in[3];
    const float* eps = (const float*)d_in[4];
    float* y = (float*)d_out;
    char* ws = (char*)d_ws;

    unsigned short* xb    = (unsigned short*)(ws);                 //  8 MB
    unsigned short* w1bT  = (unsigned short*)(ws + 8388608);       // 32 MB  [E][H][D]
    unsigned short* w2bT  = (unsigned short*)(ws + 41943040);      // 32 MB  [E][D][H]
    unsigned short* hbuf  = (unsigned short*)(ws + 75497472);      // 32 MB  [TK][H]
    unsigned short* outp0 = (unsigned short*)(ws + 109051904);     // 16 MB  [TK][D] split 0
    unsigned short* outp1 = (unsigned short*)(ws + 8388608);       // 16 MB  split 1 (reuses w1bT, dead after GEMM1)
    int*   top_i    = (int*)(ws + 125829120);
    float* top_g    = (float*)(ws + 125861888);
    int*   row_token= (int*)(ws + 125894656);
    int*   pair_pos = (int*)(ws + 125927424);
    float* stats_f  = (float*)(ws + 125960192);
    int*   stats_i  = (int*)(ws + 125960192 + 128);

    zero_stats<<<1, 256, 0, stream>>>((int*)(ws + 125960192));
    conv_transpose<<<dim3(32, 16, 8), 256, 0, stream>>>(w1, w1bT, 1024, 2048);
    conv_transpose<<<dim3(16, 32, 8), 256, 0, stream>>>(w2, w2bT, 2048, 1024);
    gating<<<1024, 256, 0, stream>>>(x, wg, eps, stats_f, stats_i, top_i, top_g, xb);
    offsets_loss<<<1, 64, 0, stream>>>(stats_f, stats_i, y + (size_t)TT * DD);
    scatter<<<16, 256, 0, stream>>>(top_i, stats_i, row_token, pair_pos);
    // GEMM1: [pairs,1024] x [2048,1024]^T -> hbuf, relu, gathered A. 8e x 8n x 5m slots.
    gemm320<1024, 1, 8, true,  true ><<<320, 512, 0, stream>>>(
        xb, w1bT, hbuf, 0, row_token, stats_i);
    // GEMM2: [pairs,2048] x [1024,2048]^T -> outp0/outp1 (split-K=2). 8e x (4n x 2s) x 5m.
    gemm320<2048, 2, 4, false, false><<<320, 512, 0, stream>>>(
        hbuf, w2bT, outp0, (long long)(outp1 - outp0), row_token, stats_i);
    combine<<<4096, 256, 0, stream>>>(outp0, outp1, pair_pos, top_g, y);
}

// Round 9
// 202.843 us; speedup vs baseline: 1.1704x; 1.0630x over previous
//
#include <hip/hip_runtime.h>

// Problem constants
#define TT 4096      // tokens (B*L)
#define DD 1024      // model dim
#define HH 2048      // hidden dim
#define EE 8         // experts
#define TK 8192      // T*K pairs (K=2)

typedef short  bf16x8 __attribute__((ext_vector_type(8)));
typedef float  f32x4  __attribute__((ext_vector_type(4)));

__device__ __forceinline__ unsigned short f2b(float f) {
    unsigned int u = __float_as_uint(f);
    unsigned int r = (u + 0x7fffu + ((u >> 16) & 1u)) >> 16;  // RNE
    return (unsigned short)r;
}
__device__ __forceinline__ float b2f(unsigned short b) {
    return __uint_as_float(((unsigned int)b) << 16);
}

#define GLOAD_LDS16(SRC, DST) __builtin_amdgcn_global_load_lds( \
    (const __attribute__((address_space(1))) unsigned int*)(SRC), \
    (__attribute__((address_space(3))) unsigned int*)(DST), 16, 0, 0)

// ------------- weight transpose + bf16 convert: src [E][Kd][Nd] -> dst [E][Nd][Kd] -------------
// First launch also zeroes the stats block (zstats != nullptr).
__global__ void conv_transpose(const float* __restrict__ src, unsigned short* __restrict__ dst,
                               int Kd, int Nd, int* zstats) {
    if (zstats && blockIdx.x == 0 && blockIdx.y == 0 && blockIdx.z == 0 && threadIdx.x < 192)
        zstats[threadIdx.x] = 0;
    int e  = blockIdx.z;
    int n0 = blockIdx.x * 64;
    int k0 = blockIdx.y * 64;
    const float* s = src + (size_t)e * Kd * Nd;
    unsigned short* d = dst + (size_t)e * Kd * Nd;
    __shared__ float tile[64][65];
    int c  = threadIdx.x & 63;
    int r4 = threadIdx.x >> 6;
#pragma unroll
    for (int i = 0; i < 16; i++) {
        int r = r4 + i * 4;
        tile[r][c] = s[(size_t)(k0 + r) * Nd + n0 + c];
    }
    __syncthreads();
#pragma unroll
    for (int i = 0; i < 16; i++) {
        int r = r4 + i * 4;
        d[(size_t)(n0 + r) * Kd + k0 + c] = f2b(tile[c][r]);
    }
}

// ---------------- gating (one token per wave) + fused x->bf16 convert ----------------
__global__ __launch_bounds__(256) void gating(const float* __restrict__ x, const float* __restrict__ wg,
                       const float* __restrict__ eps,
                       float* __restrict__ stats_f, int* __restrict__ stats_i,
                       int* __restrict__ top_i, float* __restrict__ top_g,
                       unsigned short* __restrict__ xb) {
    __shared__ float l_psum[8], l_gsum[8], l_zl;
    __shared__ int   l_cr[8], l_cp[8];
    int tid = threadIdx.x;
    if (tid < 8) { l_psum[tid] = 0.f; l_gsum[tid] = 0.f; l_cr[tid] = 0; l_cp[tid] = 0; }
    if (tid == 0) l_zl = 0.f;
    __syncthreads();
    int wave = tid >> 6, lane = tid & 63;
    int t = blockIdx.x * 4 + wave;
    const float* xr = x + (size_t)t * DD;
    unsigned short* xbr = xb + (size_t)t * DD;
    float acc[16];
#pragma unroll
    for (int j = 0; j < 16; j++) acc[j] = 0.f;
#pragma unroll
    for (int i = 0; i < 16; i++) {
        int dd = lane + i * 64;
        float xv = xr[dd];
        xbr[dd] = f2b(xv);
        const float4* wr = (const float4*)(wg + dd * 16);
        float4 w0 = wr[0], w1 = wr[1], w2 = wr[2], w3 = wr[3];
        acc[0]  += xv * w0.x; acc[1]  += xv * w0.y; acc[2]  += xv * w0.z; acc[3]  += xv * w0.w;
        acc[4]  += xv * w1.x; acc[5]  += xv * w1.y; acc[6]  += xv * w1.z; acc[7]  += xv * w1.w;
        acc[8]  += xv * w2.x; acc[9]  += xv * w2.y; acc[10] += xv * w2.z; acc[11] += xv * w2.w;
        acc[12] += xv * w3.x; acc[13] += xv * w3.y; acc[14] += xv * w3.z; acc[15] += xv * w3.w;
    }
#pragma unroll
    for (int j = 0; j < 16; j++)
#pragma unroll
        for (int o = 32; o > 0; o >>= 1) acc[j] += __shfl_xor(acc[j], o, 64);
    if (lane == 0) {
        float lg[8], p[8];
        float mx = -1e30f;
        for (int e2 = 0; e2 < 8; e2++) {
            float raw = acc[8 + e2];
            float sp = (raw > 20.f) ? raw : log1pf(__expf(raw));
            float l = acc[e2] + eps[(size_t)t * 8 + e2] * (sp + 0.01f);
            lg[e2] = l; mx = fmaxf(mx, l);
        }
        float se = 0.f;
        for (int e2 = 0; e2 < 8; e2++) { p[e2] = __expf(lg[e2] - mx); se += p[e2]; }
        float lse = mx + logf(se);
        float inv = 1.f / se;
        for (int e2 = 0; e2 < 8; e2++) p[e2] *= inv;
        int i0 = 0;
        for (int e2 = 1; e2 < 8; e2++) if (p[e2] > p[i0]) i0 = e2;
        int i1 = (i0 == 0) ? 1 : 0;
        for (int e2 = 0; e2 < 8; e2++) if (e2 != i0 && p[e2] > p[i1]) i1 = e2;
        float g0 = p[i0], g1 = p[i1];
        top_i[t * 2] = i0; top_i[t * 2 + 1] = i1;
        top_g[t * 2] = g0; top_g[t * 2 + 1] = g1;
        for (int e2 = 0; e2 < 8; e2++) atomicAdd(&l_psum[e2], p[e2]);
        atomicAdd(&l_gsum[i0], g0); atomicAdd(&l_gsum[i1], g1);
        atomicAdd(&l_zl, lse * lse);
        atomicAdd(&l_cr[i0], 1); atomicAdd(&l_cr[i1], 1);
        if (g0 > 0.f) atomicAdd(&l_cp[i0], 1);
        if (g1 > 0.f) atomicAdd(&l_cp[i1], 1);
    }
    __syncthreads();
    if (tid < 8) {
        atomicAdd(&stats_f[tid],      l_psum[tid]);
        atomicAdd(&stats_f[8 + tid],  l_gsum[tid]);
        atomicAdd(&stats_i[tid],      l_cr[tid]);
        atomicAdd(&stats_i[8 + tid],  l_cp[tid]);
    }
    if (tid == 0) atomicAdd(&stats_f[16], l_zl);
}

// ---------------- scatter pairs + offsets + loss (fused) ----------------
__global__ void scatter(const int* __restrict__ top_i, int* __restrict__ stats_i,
                        const float* __restrict__ stats_f,
                        int* __restrict__ row_token, int* __restrict__ pair_pos,
                        float* __restrict__ loss_out) {
    __shared__ int lcnt[8], lbase[8], soffs[9];
    int tid = threadIdx.x;
    if (tid < 8) lcnt[tid] = 0;
    if (tid == 0) {
        int off = 0;
        for (int e = 0; e < 8; e++) { soffs[e] = off; off += stats_i[e]; }
        soffs[8] = off;
    }
    __syncthreads();
    int t = blockIdx.x * 256 + tid;
    int e0 = top_i[t * 2], e1 = top_i[t * 2 + 1];
    int p0 = atomicAdd(&lcnt[e0], 1);
    int p1 = atomicAdd(&lcnt[e1], 1);
    __syncthreads();
    if (tid < 8) lbase[tid] = atomicAdd(&stats_i[16 + tid], lcnt[tid]);
    __syncthreads();
    int idx0 = soffs[e0] + lbase[e0] + p0;
    int idx1 = soffs[e1] + lbase[e1] + p1;
    row_token[idx0] = t;
    row_token[idx1] = t;
    pair_pos[t * 2] = idx0;
    pair_pos[t * 2 + 1] = idx1;
    if (blockIdx.x == 0 && tid == 0) {
        for (int e = 0; e < 9; e++) stats_i[24 + e] = soffs[e];
        float gs = 0.f;
        for (int e = 0; e < 8; e++) gs += stats_f[8 + e];
        float var = 0.f;
        for (int e = 0; e < 8; e++) {
            float gn = stats_f[8 + e] / gs;
            float d = gn - 0.125f;
            var += d * d;
        }
        var /= 7.f;
        float cv = var / (0.015625f + 1e-10f);
        float ps = 0.f, cs = 0.f;
        for (int e = 0; e < 8; e++) { ps += stats_f[e]; cs += (float)stats_i[8 + e]; }
        float dot = 0.f;
        for (int e = 0; e < 8; e++) dot += (stats_f[e] / ps) * ((float)stats_i[8 + e] / cs);
        float sw = (1.f - dot) * 8.f;
        float zl = stats_f[16] / (float)TT;
        *loss_out = 0.01f * cv + 0.1f * sw + 0.0001f * zl;
    }
}

// ============ grouped GEMM: 256 main blocks (256x256, 8-phase, R5 ledger) + 256 tail blocks
// (64x256, 2-phase) covering rows [1024, 1280) of oversized experts. ============
// Mains: lin<256: e=lin&7 (XCD-pinned), rem=lin>>3: q=rem&7, rt=rem>>3 (rows rt*256..+256, rt<4).
// Tails: t=lin-256: e=t&7, rem=t>>3: q=rem&7, s=rem>>3 (rows 1024+s*64..+64); exit if empty.
template<int KTOT, int KSPLITS, int NTILES, bool GATHER, bool RELU>
__global__ __launch_bounds__(512, 1) void gemm_mt(
    const unsigned short* __restrict__ A,
    const unsigned short* __restrict__ Bt,
    unsigned short* __restrict__ C, long long split_stride,
    const int* __restrict__ row_token, const int* __restrict__ stats_i) {
    constexpr int KD   = KTOT / KSPLITS;   // K per block (1024)
    constexpr int NK   = KD / 64;          // 16
    constexpr int NI   = NK / 2;           // 8
    constexpr int NDIM = NTILES * 256;
    static_assert(NTILES * KSPLITS == 8, "q must span 8");

    __shared__ __align__(16) unsigned short Al[2 * 256 * 64];
    __shared__ __align__(16) unsigned short Bl[2 * 256 * 64];

    const int* offs = stats_i + 24;
    int tid = threadIdx.x;
    int lane = tid & 63, wave = tid >> 6;

    if (blockIdx.x < 256) {
        // ===================== MAIN: 256x256, 8-phase (R5 ledger, verbatim) =====================
        int lin = blockIdx.x;
        int e   = lin & 7;
        int rem = lin >> 3;
        int q4  = rem & 7;
        int rt  = rem >> 3;                // 0..3
        int n0  = (q4 % NTILES) * 256;
        int split = q4 / NTILES;
        int off = offs[e];
        int ne  = offs[e + 1] - off;
        if (rt * 256 >= ne) return;

        int wm = wave >> 2, wn = wave & 3;

        const unsigned short* Asrc[4];
#pragma unroll
        for (int i = 0; i < 4; i++) {
            int glin = i * 512 + tid, row = glin >> 3, sl = glin & 7, g = sl ^ (row & 7);
            int arow;
            if (GATHER) arow = row_token[min(off + rt * 256 + row, TK - 1)];
            else        arow = min(off + rt * 256 + row, TK - 1);
            Asrc[i] = A + (size_t)arow * KTOT + split * KD + g * 8;
        }
        const unsigned short* Bte = Bt + (size_t)e * NDIM * KTOT;
        const unsigned short* Bsrc[4];
#pragma unroll
        for (int i = 0; i < 4; i++) {
            int glin = i * 512 + tid, row = glin >> 3, sl = glin & 7, g = sl ^ (row & 7);
            Bsrc[i] = Bte + (size_t)(n0 + row) * KTOT + split * KD + g * 8;
        }

        f32x4 acc[8][4];
#pragma unroll
        for (int m = 0; m < 8; m++)
#pragma unroll
            for (int n = 0; n < 4; n++)
#pragma unroll
                for (int i = 0; i < 4; i++) acc[m][n][i] = 0.f;

        bf16x8 bv[2][4], av[2][2];

#define STG_A(SLOT, KT, CC) GLOAD_LDS16(Asrc[CC] + (KT) * 64, Al + (SLOT) * 16384 + (CC) * 4096 + wave * 512)
#define STG_B(SLOT, KT, CC) GLOAD_LDS16(Bsrc[CC] + (KT) * 64, Bl + (SLOT) * 16384 + (CC) * 4096 + wave * 512)

#define LOAD_B(SLOT) do { \
    _Pragma("unroll") for (int kk2 = 0; kk2 < 2; kk2++) \
    _Pragma("unroll") for (int n = 0; n < 4; n++) { \
        int row = wn * 64 + n * 16 + (lane & 15); \
        int g = (kk2 * 4 + (lane >> 4)) ^ (row & 7); \
        bv[kk2][n] = *(const bf16x8*)(Bl + (SLOT) * 16384 + row * 64 + g * 8); \
    } } while (0)

#define LOAD_AQ(SLOT, QQ) do { \
    _Pragma("unroll") for (int kk2 = 0; kk2 < 2; kk2++) \
    _Pragma("unroll") for (int mi = 0; mi < 2; mi++) { \
        int row = wm * 128 + (QQ) * 32 + mi * 16 + (lane & 15); \
        int g = (kk2 * 4 + (lane >> 4)) ^ (row & 7); \
        av[kk2][mi] = *(const bf16x8*)(Al + (SLOT) * 16384 + row * 64 + g * 8); \
    } } while (0)

#define MFMA_Q(QQ) do { \
    _Pragma("unroll") for (int kk2 = 0; kk2 < 2; kk2++) \
    _Pragma("unroll") for (int mi = 0; mi < 2; mi++) \
    _Pragma("unroll") for (int n = 0; n < 4; n++) \
        acc[(QQ) * 2 + mi][n] = __builtin_amdgcn_mfma_f32_16x16x32_bf16(av[kk2][mi], bv[kk2][n], acc[(QQ) * 2 + mi][n], 0, 0, 0); \
    } while (0)

#define PHASE(SLOT, QQ, STAGE_STMT, WAIT_STMT) do { \
    if ((QQ) == 0) LOAD_B(SLOT); \
    LOAD_AQ(SLOT, QQ); \
    STAGE_STMT; \
    __builtin_amdgcn_s_barrier(); \
    asm volatile("s_waitcnt lgkmcnt(0)" ::: "memory"); \
    __builtin_amdgcn_s_setprio(1); \
    MFMA_Q(QQ); \
    __builtin_amdgcn_s_setprio(0); \
    WAIT_STMT; \
    __builtin_amdgcn_s_barrier(); \
    } while (0)

        // prologue: K0 full -> slot0; K1 all but {A1,A3} -> slot1 (14 loads; wait oldest 8)
#pragma unroll
        for (int c = 0; c < 4; c++) STG_B(0, 0, c);
#pragma unroll
        for (int c = 0; c < 4; c++) STG_A(0, 0, c);
#pragma unroll
        for (int c = 0; c < 4; c++) STG_B(1, 1, c);
        STG_A(1, 1, 0); STG_A(1, 1, 2);
        asm volatile("s_waitcnt vmcnt(6)" ::: "memory");
        __builtin_amdgcn_s_barrier();

#pragma unroll 1
        for (int it = 0; it < NI; ++it) {
            int u = 2 * it, v = u + 1;
            bool ns = (it + 1 < NI);
            PHASE(0, 0, { STG_A(1, v, 1); STG_A(1, v, 3); }, {});
            PHASE(0, 1, { if (ns) { STG_B(0, u + 2, 0); STG_B(0, u + 2, 1); } }, {});
            PHASE(0, 2, { if (ns) { STG_B(0, u + 2, 2); STG_B(0, u + 2, 3); } }, {});
            PHASE(0, 3, { if (ns) { STG_A(0, u + 2, 0); STG_A(0, u + 2, 2); } },
                        { if (ns) asm volatile("s_waitcnt vmcnt(6)" ::: "memory");
                          else    asm volatile("s_waitcnt vmcnt(0)" ::: "memory"); });
            PHASE(1, 0, { if (ns) { STG_A(0, u + 2, 1); STG_A(0, u + 2, 3); } }, {});
            PHASE(1, 1, { if (ns) { STG_B(1, v + 2, 0); STG_B(1, v + 2, 1); } }, {});
            PHASE(1, 2, { if (ns) { STG_B(1, v + 2, 2); STG_B(1, v + 2, 3); } }, {});
            PHASE(1, 3, { if (ns) { STG_A(1, v + 2, 0); STG_A(1, v + 2, 2); } },
                        { if (ns) asm volatile("s_waitcnt vmcnt(6)" ::: "memory"); });
        }
#undef PHASE
#undef MFMA_Q
#undef LOAD_AQ
#undef LOAD_B
#undef STG_A
#undef STG_B

        unsigned short* Cb = C + (ptrdiff_t)split * split_stride;
#pragma unroll
        for (int m = 0; m < 8; m++) {
            int rr0 = rt * 256 + wm * 128 + m * 16 + (lane >> 4) * 4;
#pragma unroll
            for (int i = 0; i < 4; i++) {
                if (rr0 + i < ne) {
                    size_t grow = (size_t)(off + rr0 + i);
#pragma unroll
                    for (int n = 0; n < 4; n++) {
                        int col = n0 + wn * 64 + n * 16 + (lane & 15);
                        float vvv = acc[m][n][i];
                        if (RELU) vvv = fmaxf(vvv, 0.f);
                        Cb[grow * NDIM + col] = f2b(vvv);
                    }
                }
            }
        }
    } else {
        // ===================== TAIL: 64x256, 2-phase double-buffered =====================
        int t   = blockIdx.x - 256;
        int e   = t & 7;
        int rem = t >> 3;
        int q4  = rem & 7;
        int s   = rem >> 3;                // 0..3
        int n0  = (q4 % NTILES) * 256;
        int split = q4 / NTILES;
        int off = offs[e];
        int ne  = offs[e + 1] - off;
        int m0  = 1024 + s * 64;
        if (m0 >= ne) return;

        int wm = wave >> 2, wn = wave & 3;

        const unsigned short* Asrc;
        {
            int row = tid >> 3, sl = tid & 7, g = sl ^ (row & 7);
            int arow;
            if (GATHER) arow = row_token[min(off + m0 + row, TK - 1)];
            else        arow = min(off + m0 + row, TK - 1);
            Asrc = A + (size_t)arow * KTOT + split * KD + g * 8;
        }
        const unsigned short* Bte = Bt + (size_t)e * NDIM * KTOT;
        const unsigned short* Bsrc[4];
#pragma unroll
        for (int i = 0; i < 4; i++) {
            int glin = i * 512 + tid, row = glin >> 3, sl = glin & 7, g = sl ^ (row & 7);
            Bsrc[i] = Bte + (size_t)(n0 + row) * KTOT + split * KD + g * 8;
        }

        f32x4 acc2[2][4];
#pragma unroll
        for (int m = 0; m < 2; m++)
#pragma unroll
            for (int n = 0; n < 4; n++)
#pragma unroll
                for (int i = 0; i < 4; i++) acc2[m][n][i] = 0.f;

#define TSTG(BUF, KT) do { \
    GLOAD_LDS16(Asrc + (KT) * 64, Al + (BUF) * 4096 + wave * 512); \
    _Pragma("unroll") for (int c_ = 0; c_ < 4; c_++) \
        GLOAD_LDS16(Bsrc[c_] + (KT) * 64, Bl + (BUF) * 16384 + c_ * 4096 + wave * 512); \
} while (0)

        TSTG(0, 0);
        asm volatile("s_waitcnt vmcnt(0)" ::: "memory");
        __builtin_amdgcn_s_barrier();

#pragma unroll 1
        for (int kt = 0; kt < NK; ++kt) {
            if (kt + 1 < NK) TSTG((kt & 1) ^ 1, kt + 1);
            int B = kt & 1;
            bf16x8 a2[2][2], b2[2][4];
#pragma unroll
            for (int kk2 = 0; kk2 < 2; kk2++) {
#pragma unroll
                for (int mi = 0; mi < 2; mi++) {
                    int row = wm * 32 + mi * 16 + (lane & 15);
                    int g = (kk2 * 4 + (lane >> 4)) ^ (row & 7);
                    a2[kk2][mi] = *(const bf16x8*)(Al + B * 4096 + row * 64 + g * 8);
                }
#pragma unroll
                for (int n = 0; n < 4; n++) {
                    int row = wn * 64 + n * 16 + (lane & 15);
                    int g = (kk2 * 4 + (lane >> 4)) ^ (row & 7);
                    b2[kk2][n] = *(const bf16x8*)(Bl + B * 16384 + row * 64 + g * 8);
                }
            }
#pragma unroll
            for (int kk2 = 0; kk2 < 2; kk2++)
#pragma unroll
                for (int mi = 0; mi < 2; mi++)
#pragma unroll
                    for (int n = 0; n < 4; n++)
                        acc2[mi][n] = __builtin_amdgcn_mfma_f32_16x16x32_bf16(a2[kk2][mi], b2[kk2][n], acc2[mi][n], 0, 0, 0);
            asm volatile("s_waitcnt vmcnt(0) lgkmcnt(0)" ::: "memory");
            __builtin_amdgcn_s_barrier();
        }
#undef TSTG

        unsigned short* Cb = C + (ptrdiff_t)split * split_stride;
#pragma unroll
        for (int mi = 0; mi < 2; mi++) {
            int rr0 = m0 + wm * 32 + mi * 16 + (lane >> 4) * 4;
#pragma unroll
            for (int i = 0; i < 4; i++) {
                if (rr0 + i < ne) {
                    size_t grow = (size_t)(off + rr0 + i);
#pragma unroll
                    for (int n = 0; n < 4; n++) {
                        int col = n0 + wn * 64 + n * 16 + (lane & 15);
                        float vvv = acc2[mi][n][i];
                        if (RELU) vvv = fmaxf(vvv, 0.f);
                        Cb[grow * NDIM + col] = f2b(vvv);
                    }
                }
            }
        }
    }
}

// ---------------- gated combine (sums the two GEMM2 K-splits) ----------------
__global__ void combine(const unsigned short* __restrict__ o0,
                        const unsigned short* __restrict__ o1,
                        const int* __restrict__ pair_pos, const float* __restrict__ top_g,
                        float* __restrict__ y) {
    int t = blockIdx.x;
    int tid = threadIdx.x;
    int i0 = pair_pos[t * 2], i1 = pair_pos[t * 2 + 1];
    float g0 = top_g[t * 2], g1 = top_g[t * 2 + 1];
    int d0 = tid * 4;
    ushort4 a0 = *(const ushort4*)(o0 + (size_t)i0 * DD + d0);
    ushort4 a1 = *(const ushort4*)(o1 + (size_t)i0 * DD + d0);
    ushort4 b0 = *(const ushort4*)(o0 + (size_t)i1 * DD + d0);
    ushort4 b1 = *(const ushort4*)(o1 + (size_t)i1 * DD + d0);
    float4 o;
    o.x = g0 * (b2f(a0.x) + b2f(a1.x)) + g1 * (b2f(b0.x) + b2f(b1.x));
    o.y = g0 * (b2f(a0.y) + b2f(a1.y)) + g1 * (b2f(b0.y) + b2f(b1.y));
    o.z = g0 * (b2f(a0.z) + b2f(a1.z)) + g1 * (b2f(b0.z) + b2f(b1.z));
    o.w = g0 * (b2f(a0.w) + b2f(a1.w)) + g1 * (b2f(b0.w) + b2f(b1.w));
    *(float4*)(y + (size_t)t * DD + d0) = o;
}

extern "C" void kernel_launch(void* const* d_in, const int* in_sizes, int n_in,
                              void* d_out, int out_size, void* d_ws, size_t ws_size,
                              hipStream_t stream) {
    const float* x   = (const float*)d_in[0];
    const float* wg  = (const float*)d_in[1];
    const float* w1  = (const float*)d_in[2];
    const float* w2  = (const float*)d_in[3];
    const float* eps = (const float*)d_in[4];
    float* y = (float*)d_out;
    char* ws = (char*)d_ws;

    unsigned short* xb    = (unsigned short*)(ws);                 //  8 MB
    unsigned short* w1bT  = (unsigned short*)(ws + 8388608);       // 32 MB  [E][H][D]
    unsigned short* w2bT  = (unsigned short*)(ws + 41943040);      // 32 MB  [E][D][H]
    unsigned short* hbuf  = (unsigned short*)(ws + 75497472);      // 32 MB  [TK][H]
    unsigned short* outp0 = (unsigned short*)(ws + 109051904);     // 16 MB  [TK][D] split 0
    unsigned short* outp1 = (unsigned short*)(ws + 8388608);       // 16 MB  split 1 (reuses w1bT, dead after GEMM1)
    int*   top_i    = (int*)(ws + 125829120);
    float* top_g    = (float*)(ws + 125861888);
    int*   row_token= (int*)(ws + 125894656);
    int*   pair_pos = (int*)(ws + 125927424);
    float* stats_f  = (float*)(ws + 125960192);
    int*   stats_i  = (int*)(ws + 125960192 + 128);

    conv_transpose<<<dim3(32, 16, 8), 256, 0, stream>>>(w1, w1bT, 1024, 2048, (int*)(ws + 125960192));
    conv_transpose<<<dim3(16, 32, 8), 256, 0, stream>>>(w2, w2bT, 2048, 1024, nullptr);
    gating<<<1024, 256, 0, stream>>>(x, wg, eps, stats_f, stats_i, top_i, top_g, xb);
    scatter<<<16, 256, 0, stream>>>(top_i, stats_i, stats_f, row_token, pair_pos, y + (size_t)TT * DD);
    // GEMM1: [pairs,1024] x [2048,1024]^T -> hbuf, relu, gathered A. 256 mains + 256 tails.
    gemm_mt<1024, 1, 8, true,  true ><<<512, 512, 0, stream>>>(
        xb, w1bT, hbuf, 0, row_token, stats_i);
    // GEMM2: [pairs,2048] x [1024,2048]^T -> outp0/outp1 (split-K=2). 256 mains + 256 tails.
    gemm_mt<2048, 2, 4, false, false><<<512, 512, 0, stream>>>(
        hbuf, w2bT, outp0, (long long)(outp1 - outp0), row_token, stats_i);
    combine<<<4096, 256, 0, stream>>>(outp0, outp1, pair_pos, top_g, y);
}